// Round 14
// baseline (161.787 us; speedup 1.0000x reference)
//
#include <hip/hip_runtime.h>

// GraphConstruction: x[1,1024,1024] fp32 -> A[4096,4096] in {0,1} fp32.
// patches[n,r,k] = x[h,w], h = (n&15)*64 + (r>>2)*16 + (n>>8),
//                          w = (r&3)*256 + k*16 + ((n>>4)&15)
// LOCKED NUMERICS (R6..R13, absmax 0):
//   sq[n,k]: acc = p0^2; acc = acc + fl(p_r^2), r ascending (plain adds)
//   G: one IEEE-f32 fma per r, r ascending, per (cell,k) chain
//   d2 = fmaf(-2,G,fl(si+sj));  all_k (d2 <= 49.0f);  A symmetric -> mirror.
// R14: v_pk_fma_f32 along k (k0,k1 chains are independent accumulators ->
//   packing is associativity-free; per-chain order unchanged = bit-exact).
//   LDS re-laid transposed + k-interleaved: chunk[r][rowpair] =
//   (rowE k0, rowE k1, rowO k0, rowO k1) so pk operand pairs are adjacent
//   inside one ds_read_b128 -> zero packing moves. Reads/thread unchanged
//   (64/phase = 4x4-tile floor); fma instr 4096 -> 2048 pk.
//   Swizzle fsw(i)=i^(i>>3): b-reads exactly 2-way (free), a-reads clean,
//   staging writes 2-way (verified per-instruction below).

#define NPATCH 4096
#define BT 64
#define NPH 8
#define CH 33   // float4 chunks per r-row (32 + 1 pad)

typedef float v2f __attribute__((ext_vector_type(2)));
typedef float v4f __attribute__((ext_vector_type(4)));

__device__ __forceinline__ int fsw(int i) { return i ^ (i >> 3); }  // bijective on [0,32)

__global__ __launch_bounds__(256, 3) void adj_kernel(const float* __restrict__ x,
                                                     float* __restrict__ A) {
#pragma clang fp contract(off)
    __shared__ v4f SiT[16 * CH];
    __shared__ v4f SjT[16 * CH];
    __shared__ float sqs[2][2][BT];   // [side][kl][row]

    // linear -> lower-triangle (bi >= bj)
    int t = blockIdx.x;
    int bi = (int)((sqrtf(8.0f * (float)t + 1.0f) - 1.0f) * 0.5f);
    while ((bi + 1) * (bi + 2) / 2 <= t) ++bi;
    while (bi * (bi + 1) / 2 > t) --bi;
    int bj = t - bi * (bi + 1) / 2;

    const int i0 = bi * BT;
    const int j0 = bj * BT;
    const int tid = threadIdx.x;
    const int tx = tid & 15;       // j-cols tx*4..+3
    const int ty = tid >> 4;       // i-rows ty*4..+3
    const int cA0 = fsw(ty * 2), cA1 = fsw(ty * 2 + 1);
    const int cB0 = fsw(tx * 2), cB1 = fsw(tx * 2 + 1);

    unsigned int bad = 0u;         // bit u*4+v => some d2 > 49

    for (int kp = 0; kp < NPH; ++kp) {
        __syncthreads();
        // ---- stage: 1024 float4 global loads; scatter k-interleaved ----
        // Per write instr: banks = (4r + 4*fsw(8dd+rl>>1) + slot) mod 32,
        // r 0..15 x 4 slots -> exactly 2-way. (verified)
#pragma unroll
        for (int l = 0; l < 4; ++l) {
            int gid = l * 256 + tid;
            int side = gid >> 9;
            int q = gid & 511;             // kl(1) | r(4) | rl(4)
            int kl = q & 1;
            int r = (q >> 1) & 15;
            int rl = q >> 5;
            int k = kp * 2 + kl;
            int b = side ? bj : bi;
            int h = rl * 64 + (r >> 2) * 16 + (b >> 2);
            int w0 = (r & 3) * 256 + k * 16 + ((4 * b) & 15);
            float4 v = *(const float4*)&x[h * 1024 + w0];
            const float* vp = (const float*)&v;
            float* Sb = side ? (float*)SjT : (float*)SiT;
            int slot = (rl & 1) * 2 + kl;
#pragma unroll
            for (int dd = 0; dd < 4; ++dd) {   // elem dd -> row 16*dd+rl
                int rowpair = 8 * dd + (rl >> 1);
                Sb[(r * CH + fsw(rowpair)) * 4 + slot] = vp[dd];
            }
        }
        __syncthreads();
        // ---- sq: 128 threads, one row each, both k; plain adds r ascending ----
        if (tid < 128) {
            int side = tid >> 6;
            int row = tid & 63;
            const v4f* Sb = side ? SjT : SiT;
            int rp = fsw(row >> 1);
            int s0 = (row & 1) * 2;
            float acc0, acc1;
            {
                v4f v = Sb[rp];                 // r = 0
                float e0 = v[s0], e1 = v[s0 + 1];
                acc0 = e0 * e0;
                acc1 = e1 * e1;
            }
#pragma unroll
            for (int r = 1; r < 16; ++r) {
                v4f v = Sb[r * CH + rp];
                float e0 = v[s0], e1 = v[s0 + 1];
                float t0 = e0 * e0; acc0 = acc0 + t0;
                float t1 = e1 * e1; acc1 = acc1 + t1;
            }
            sqs[side][0][row] = acc0;
            sqs[side][1][row] = acc1;
        }
        __syncthreads();
        // ---- compute: 4x4 cells x 2 k via v_pk_fma_f32, r ascending ----
        v2f d[4][4];
#pragma unroll
        for (int u = 0; u < 4; ++u)
#pragma unroll
            for (int v = 0; v < 4; ++v) d[u][v] = (v2f)(0.0f);
#pragma unroll
        for (int r = 0; r < 16; ++r) {
            v4f a0 = SiT[r * CH + cA0];    // rows 4ty,4ty+1  (k0,k1 each)
            v4f a1 = SiT[r * CH + cA1];    // rows 4ty+2,4ty+3
            v4f b0 = SjT[r * CH + cB0];
            v4f b1 = SjT[r * CH + cB1];
            v2f ap[4] = { a0.xy, a0.zw, a1.xy, a1.zw };
            v2f bp[4] = { b0.xy, b0.zw, b1.xy, b1.zw };
#pragma unroll
            for (int u = 0; u < 4; ++u)
#pragma unroll
                for (int v = 0; v < 4; ++v)
                    asm("v_pk_fma_f32 %0, %1, %2, %0"
                        : "+v"(d[u][v]) : "v"(ap[u]), "v"(bp[v]));
        }
        // ---- fold decisions for this k-pair ----
        v4f si0 = *(const v4f*)&sqs[0][0][ty * 4];
        v4f si1 = *(const v4f*)&sqs[0][1][ty * 4];
        v4f sj0 = *(const v4f*)&sqs[1][0][tx * 4];
        v4f sj1 = *(const v4f*)&sqs[1][1][tx * 4];
#pragma unroll
        for (int u = 0; u < 4; ++u)
#pragma unroll
            for (int v = 0; v < 4; ++v) {
                float s0 = si0[u] + sj0[v];             // fl(si+sj), k0
                float s1 = si1[u] + sj1[v];             // k1
                float d20 = fmaf(-2.0f, d[u][v].x, s0); // fl(s-2G)
                float d21 = fmaf(-2.0f, d[u][v].y, s1);
                bad |= ((d20 > 49.0f) || (d21 > 49.0f)) ? (1u << (u * 4 + v)) : 0u;
            }
    }

    // ---- stores: direct + mirrored (A exactly symmetric) ----
#pragma unroll
    for (int u = 0; u < 4; ++u) {
        float4 o;
        o.x = (bad >> (u * 4 + 0)) & 1u ? 0.0f : 1.0f;
        o.y = (bad >> (u * 4 + 1)) & 1u ? 0.0f : 1.0f;
        o.z = (bad >> (u * 4 + 2)) & 1u ? 0.0f : 1.0f;
        o.w = (bad >> (u * 4 + 3)) & 1u ? 0.0f : 1.0f;
        *(float4*)&A[(size_t)(i0 + ty * 4 + u) * NPATCH + j0 + tx * 4] = o;
    }
    if (bi != bj) {
#pragma unroll
        for (int v = 0; v < 4; ++v) {
            float4 o;
            o.x = (bad >> (0 * 4 + v)) & 1u ? 0.0f : 1.0f;
            o.y = (bad >> (1 * 4 + v)) & 1u ? 0.0f : 1.0f;
            o.z = (bad >> (2 * 4 + v)) & 1u ? 0.0f : 1.0f;
            o.w = (bad >> (3 * 4 + v)) & 1u ? 0.0f : 1.0f;
            *(float4*)&A[(size_t)(j0 + tx * 4 + v) * NPATCH + i0 + ty * 4] = o;
        }
    }
}

extern "C" void kernel_launch(void* const* d_in, const int* in_sizes, int n_in,
                              void* d_out, int out_size, void* d_ws, size_t ws_size,
                              hipStream_t stream) {
    const float* x = (const float*)d_in[0];
    float* A = (float*)d_out;
    (void)d_ws; (void)ws_size;

    const int nblk = (NPATCH / BT) * (NPATCH / BT + 1) / 2;  // 2080
    adj_kernel<<<nblk, 256, 0, stream>>>(x, A);
}